// Round 1
// baseline (740.550 us; speedup 1.0000x reference)
//
#include <hip/hip_runtime.h>

#define NODES 50000
#define CH 128

// ---------------- CSR build ----------------

__global__ void zero_ints(int* p, int n) {
    int i = blockIdx.x * blockDim.x + threadIdx.x;
    if (i < n) p[i] = 0;
}

__global__ void count_deg(const int* __restrict__ ei, int E, int* __restrict__ deg) {
    int e = blockIdx.x * blockDim.x + threadIdx.x;
    if (e < E) atomicAdd(&deg[ei[E + e]], 1);
}

// single-block exclusive scan over deg -> offsets[0..N]
__global__ void scan_deg(const int* __restrict__ deg, int* __restrict__ offsets, int N) {
    __shared__ int sums[1024];
    int t = threadIdx.x;
    int chunk = (N + 1023) >> 10;
    int begin = t * chunk;
    int end = begin + chunk; if (end > N) end = N;
    int s = 0;
    if (begin < N) {
        for (int i = begin; i < end; ++i) s += deg[i];
    }
    sums[t] = s;
    __syncthreads();
    for (int off = 1; off < 1024; off <<= 1) {
        int v = (t >= off) ? sums[t - off] : 0;
        __syncthreads();
        sums[t] += v;
        __syncthreads();
    }
    int run = (t == 0) ? 0 : sums[t - 1];
    if (begin < N) {
        for (int i = begin; i < end; ++i) { offsets[i] = run; run += deg[i]; }
        if (end == N) offsets[N] = run;
    }
}

__global__ void fill_csr(const int* __restrict__ ei, int E,
                         const int* __restrict__ offsets,
                         int* __restrict__ cursor, int* __restrict__ csr) {
    int e = blockIdx.x * blockDim.x + threadIdx.x;
    if (e < E) {
        int d = ei[E + e];
        int pos = atomicAdd(&cursor[d], 1);
        csr[offsets[d] + pos] = ei[e];
    }
}

// ---------------- mean aggregation (gather over CSR) ----------------
// block = 128 threads = one node; thread t owns channel t. Coalesced 512B row reads.
__global__ void aggregate(const float* __restrict__ h, const int* __restrict__ csr,
                          const int* __restrict__ offsets, float* __restrict__ mean) {
    int i = blockIdx.x;
    int t = threadIdx.x;
    int s = offsets[i], e = offsets[i + 1];
    float acc = 0.f;
    for (int n = s; n < e; ++n) {
        int src = csr[n];
        acc += h[(size_t)src * CH + t];
    }
    float d = (float)(e - s);
    mean[(size_t)i * CH + t] = acc / fmaxf(d, 1.f);
}

// ---------------- fp32 GEMM: out[N,128] = A1@W1 + A2@W2 + bias (optional relu) ----
// 256 threads, 64-row x 128-col tile, K-chunks of 32 staged in LDS.
// Each thread: 8 rows x 4 cols = 32 accumulators.
template <bool RELU>
__global__ __launch_bounds__(256) void gemm128(
    const float* __restrict__ A1, const float* __restrict__ W1, int K1,
    const float* __restrict__ A2, const float* __restrict__ W2, int K2,
    const float* __restrict__ bias, float* __restrict__ out, int N)
{
    __shared__ float At[32][68];   // transposed A tile, padded (68*4B keeps 16B align, breaks pow2 stride)
    __shared__ float Bt[32][128];

    int tid = threadIdx.x;
    int row0 = blockIdx.x * 64;
    int colt = (tid & 31) * 4;      // 4 cols
    int rbase = (tid >> 5) * 8;     // 8 rows

    float acc[8][4];
#pragma unroll
    for (int i = 0; i < 8; ++i)
#pragma unroll
        for (int j = 0; j < 4; ++j) acc[i][j] = 0.f;

#pragma unroll 1
    for (int part = 0; part < 2; ++part) {
        const float* A = part ? A2 : A1;
        const float* W = part ? W2 : W1;
        int K = part ? K2 : K1;
        if (K == 0) continue;  // uniform across block

#pragma unroll 1
        for (int k0 = 0; k0 < K; k0 += 32) {
            __syncthreads();
            // A tile: 64 rows x 32 k = 512 float4, 2 per thread, stored transposed
#pragma unroll
            for (int i = 0; i < 2; ++i) {
                int e = tid + i * 256;
                int row = e >> 3;
                int kq = (e & 7) * 4;
                int grow = row0 + row; if (grow > N - 1) grow = N - 1;
                const float4 v = *(const float4*)(A + (size_t)grow * K + k0 + kq);
                At[kq + 0][row] = v.x;
                At[kq + 1][row] = v.y;
                At[kq + 2][row] = v.z;
                At[kq + 3][row] = v.w;
            }
            // B tile: 32 k x 128 cols = 1024 float4, 4 per thread
#pragma unroll
            for (int i = 0; i < 4; ++i) {
                int e = tid + i * 256;
                int kr = e >> 5;
                int cq = (e & 31) * 4;
                *(float4*)&Bt[kr][cq] = *(const float4*)(W + (size_t)(k0 + kr) * 128 + cq);
            }
            __syncthreads();

#pragma unroll
            for (int k = 0; k < 32; ++k) {
                float4 b = *(float4*)&Bt[k][colt];
                float4 a0 = *(float4*)&At[k][rbase];
                float4 a1 = *(float4*)&At[k][rbase + 4];
                float a[8] = {a0.x, a0.y, a0.z, a0.w, a1.x, a1.y, a1.z, a1.w};
                float bb[4] = {b.x, b.y, b.z, b.w};
#pragma unroll
                for (int ri = 0; ri < 8; ++ri)
#pragma unroll
                    for (int ci = 0; ci < 4; ++ci)
                        acc[ri][ci] += a[ri] * bb[ci];
            }
        }
    }

    float4 bv = *(const float4*)(bias + colt);
    float bb[4] = {bv.x, bv.y, bv.z, bv.w};
#pragma unroll
    for (int ri = 0; ri < 8; ++ri) {
        int row = row0 + rbase + ri;
        if (row < N) {
            float4 o;
            float v0 = acc[ri][0] + bb[0];
            float v1 = acc[ri][1] + bb[1];
            float v2 = acc[ri][2] + bb[2];
            float v3 = acc[ri][3] + bb[3];
            if (RELU) {
                v0 = fmaxf(v0, 0.f); v1 = fmaxf(v1, 0.f);
                v2 = fmaxf(v2, 0.f); v3 = fmaxf(v3, 0.f);
            }
            o.x = v0; o.y = v1; o.z = v2; o.w = v3;
            *(float4*)(out + (size_t)row * 128 + colt) = o;
        }
    }
}

// ---------------- classifier: out[e] = dot(h2[a], h2[b]) over 128 ch ----------------
// 32 lanes per edge, float4 per lane, shuffle reduce.
__global__ void classify(const float* __restrict__ h2, const int* __restrict__ eli,
                         int EL, float* __restrict__ out) {
    int gt = blockIdx.x * blockDim.x + threadIdx.x;
    int g = gt >> 5;
    int lane = gt & 31;
    if (g >= EL) return;
    int a = eli[g], b = eli[EL + g];
    float4 va = *((const float4*)(h2 + (size_t)a * 128) + lane);
    float4 vb = *((const float4*)(h2 + (size_t)b * 128) + lane);
    float p = va.x * vb.x + va.y * vb.y + va.z * vb.z + va.w * vb.w;
    p += __shfl_down(p, 16, 32);
    p += __shfl_down(p, 8, 32);
    p += __shfl_down(p, 4, 32);
    p += __shfl_down(p, 2, 32);
    p += __shfl_down(p, 1, 32);
    if (lane == 0) out[g] = p;
}

extern "C" void kernel_launch(void* const* d_in, const int* in_sizes, int n_in,
                              void* d_out, int out_size, void* d_ws, size_t ws_size,
                              hipStream_t stream) {
    const float* x     = (const float*)d_in[0];
    const int*   ei    = (const int*)d_in[1];
    const int*   eli   = (const int*)d_in[2];
    const float* W_lin = (const float*)d_in[3];
    const float* b_lin = (const float*)d_in[4];
    const float* W1l   = (const float*)d_in[5];
    const float* b1    = (const float*)d_in[6];
    const float* W1r   = (const float*)d_in[7];
    const float* W2l   = (const float*)d_in[8];
    const float* b2    = (const float*)d_in[9];
    const float* W2r   = (const float*)d_in[10];
    float* out = (float*)d_out;

    const int E  = in_sizes[1] / 2;
    const int EL = in_sizes[2] / 2;
    const int N  = NODES;

    char* ws = (char*)d_ws;
    size_t off = 0;
    auto alloc = [&](size_t bytes) -> void* {
        void* p = ws + off;
        off += (bytes + 255) & ~(size_t)255;
        return p;
    };
    float* bufA = (float*)alloc((size_t)N * CH * sizeof(float));  // h0 / mean2
    float* bufB = (float*)alloc((size_t)N * CH * sizeof(float));  // mean1 / h2
    float* bufC = (float*)alloc((size_t)N * CH * sizeof(float));  // h1
    int* deg     = (int*)alloc((size_t)2 * N * sizeof(int));      // deg + cursor contiguous
    int* cursor  = deg + N;
    int* offsets = (int*)alloc((size_t)(N + 16) * sizeof(int));
    int* csr     = (int*)alloc((size_t)E * sizeof(int));
    (void)ws_size; (void)n_in; (void)out_size;

    // ---- build CSR (rebuilt every call; ws is poisoned between calls) ----
    zero_ints<<<dim3((2 * N + 255) / 256), dim3(256), 0, stream>>>(deg, 2 * N);
    count_deg<<<dim3((E + 255) / 256), dim3(256), 0, stream>>>(ei, E, deg);
    scan_deg<<<dim3(1), dim3(1024), 0, stream>>>(deg, offsets, N);
    fill_csr<<<dim3((E + 255) / 256), dim3(256), 0, stream>>>(ei, E, offsets, cursor, csr);

    const int gblocks = (N + 63) / 64;

    // h0 = x @ W_lin + b_lin
    gemm128<false><<<dim3(gblocks), dim3(256), 0, stream>>>(
        x, W_lin, 384, nullptr, nullptr, 0, b_lin, bufA, N);

    // layer 1: mean1 = agg(h0); h1 = relu(mean1@W1l + h0@W1r + b1)
    aggregate<<<dim3(N), dim3(128), 0, stream>>>(bufA, csr, offsets, bufB);
    gemm128<true><<<dim3(gblocks), dim3(256), 0, stream>>>(
        bufB, W1l, 128, bufA, W1r, 128, b1, bufC, N);

    // layer 2: mean2 = agg(h1); h2 = mean2@W2l + h1@W2r + b2
    aggregate<<<dim3(N), dim3(128), 0, stream>>>(bufC, csr, offsets, bufA);
    gemm128<false><<<dim3(gblocks), dim3(256), 0, stream>>>(
        bufA, W2l, 128, bufC, W2r, 128, b2, bufB, N);

    // classifier
    long long cls_threads = (long long)EL * 32;
    classify<<<dim3((int)((cls_threads + 255) / 256)), dim3(256), 0, stream>>>(
        bufB, eli, EL, out);
}

// Round 2
// 505.700 us; speedup vs baseline: 1.4644x; 1.4644x over previous
//
#include <hip/hip_runtime.h>

#define NODES 50000
#define CH 128

using frag_ab = __attribute__((ext_vector_type(8))) short;   // 8 bf16
using frag_cd = __attribute__((ext_vector_type(4))) float;   // 4 fp32

__device__ __forceinline__ float bf2f(ushort u) {
    union { unsigned u; float f; } v; v.u = ((unsigned)u) << 16; return v.f;
}
__device__ __forceinline__ ushort f2bf(float f) {
    union { float f; unsigned u; } v; v.f = f;
    unsigned r = v.u + 0x7fff + ((v.u >> 16) & 1);   // RNE
    return (ushort)(r >> 16);
}

// ---------------- prep: fp32 -> bf16 conversions ----------------

__global__ void f2bf_vec4(const float* __restrict__ in, ushort* __restrict__ out, int n4) {
    int i = blockIdx.x * blockDim.x + threadIdx.x;
    if (i < n4) {
        float4 v = ((const float4*)in)[i];
        ushort4 o;
        o.x = f2bf(v.x); o.y = f2bf(v.y); o.z = f2bf(v.z); o.w = f2bf(v.w);
        ((ushort4*)out)[i] = o;
    }
}

// W [K,128] fp32 -> Wt [128,K] bf16 (B^T layout for MFMA b-frags)
__global__ void transpose_w(const float* __restrict__ W, ushort* __restrict__ Wt, int K) {
    int k = blockIdx.x * blockDim.y + threadIdx.y;
    int n = threadIdx.x;
    if (k < K) Wt[(size_t)n * K + k] = f2bf(W[(size_t)k * 128 + n]);
}

// ---------------- CSR build ----------------

__global__ void zero_ints(int* p, int n) {
    int i = blockIdx.x * blockDim.x + threadIdx.x;
    if (i < n) p[i] = 0;
}

__global__ void count_deg(const int* __restrict__ ei, int E, int* __restrict__ deg) {
    int e = blockIdx.x * blockDim.x + threadIdx.x;
    if (e < E) atomicAdd(&deg[ei[E + e]], 1);
}

__global__ void scan_deg(const int* __restrict__ deg, int* __restrict__ offsets, int N) {
    __shared__ int sums[1024];
    int t = threadIdx.x;
    int chunk = (N + 1023) >> 10;
    int begin = t * chunk;
    int end = begin + chunk; if (end > N) end = N;
    int s = 0;
    if (begin < N) for (int i = begin; i < end; ++i) s += deg[i];
    sums[t] = s;
    __syncthreads();
    for (int off = 1; off < 1024; off <<= 1) {
        int v = (t >= off) ? sums[t - off] : 0;
        __syncthreads();
        sums[t] += v;
        __syncthreads();
    }
    int run = (t == 0) ? 0 : sums[t - 1];
    if (begin < N) {
        for (int i = begin; i < end; ++i) { offsets[i] = run; run += deg[i]; }
        if (end == N) offsets[N] = run;
    }
}

__global__ void fill_csr(const int* __restrict__ ei, int E,
                         const int* __restrict__ offsets,
                         int* __restrict__ cursor, int* __restrict__ csr) {
    int e = blockIdx.x * blockDim.x + threadIdx.x;
    if (e < E) {
        int d = ei[E + e];
        int pos = atomicAdd(&cursor[d], 1);
        csr[offsets[d] + pos] = ei[e];
    }
}

// ---------------- mean aggregation over CSR, bf16 in/out ----------------
// one wave per node; lane reads ushort2 (4B) -> 64 lanes cover the 256B row.
__global__ __launch_bounds__(256) void aggregate_bf(
    const ushort* __restrict__ h, const int* __restrict__ csr,
    const int* __restrict__ offsets, ushort* __restrict__ mean) {
    int node = blockIdx.x * 4 + (threadIdx.x >> 6);
    int lane = threadIdx.x & 63;
    if (node >= NODES) return;
    int s = offsets[node], e = offsets[node + 1];
    float a0 = 0.f, a1 = 0.f;
    int n = s;
    for (; n + 1 < e; n += 2) {
        int s0 = csr[n], s1 = csr[n + 1];
        uint v0 = *(const uint*)(h + (size_t)s0 * CH + lane * 2);
        uint v1 = *(const uint*)(h + (size_t)s1 * CH + lane * 2);
        a0 += bf2f((ushort)(v0 & 0xffff)) + bf2f((ushort)(v1 & 0xffff));
        a1 += bf2f((ushort)(v0 >> 16))    + bf2f((ushort)(v1 >> 16));
    }
    if (n < e) {
        uint v0 = *(const uint*)(h + (size_t)csr[n] * CH + lane * 2);
        a0 += bf2f((ushort)(v0 & 0xffff));
        a1 += bf2f((ushort)(v0 >> 16));
    }
    float d = fmaxf((float)(e - s), 1.f);
    uint o = ((uint)f2bf(a1 / d) << 16) | (uint)f2bf(a0 / d);
    *(uint*)(mean + (size_t)node * CH + lane * 2) = o;
}

// ---------------- MFMA GEMM: out[N,128](bf16) = A1@W1 + A2@W2 + bias ----------------
// 128x128 tile / block, 4 waves in 2x2, each wave 4x4 grid of 16x16x32 MFMA tiles.
// A: [N,K] bf16 row-major. Wt: [128,K] bf16 (B^T). Accum fp32, optional relu.
template <bool RELU>
__global__ __launch_bounds__(256) void mfma_gemm(
    const ushort* __restrict__ A1, const ushort* __restrict__ Wt1, int K1,
    const ushort* __restrict__ A2, const ushort* __restrict__ Wt2, int K2,
    const float* __restrict__ bias, ushort* __restrict__ out, int N)
{
    __shared__ ushort As[128 * 32];
    __shared__ ushort Bs[128 * 32];
    const int tid = threadIdx.x;
    const int lane = tid & 63;
    const int wave = tid >> 6;
    const int wr = wave >> 1;
    const int wc = wave & 1;
    const int row0 = blockIdx.x * 128;
    const int l15 = lane & 15;
    const int quad = lane >> 4;

    frag_cd acc[4][4];
#pragma unroll
    for (int i = 0; i < 4; ++i)
#pragma unroll
        for (int j = 0; j < 4; ++j) acc[i][j] = (frag_cd){0.f, 0.f, 0.f, 0.f};

#pragma unroll 1
    for (int part = 0; part < 2; ++part) {
        const ushort* A  = part ? A2 : A1;
        const ushort* Wt = part ? Wt2 : Wt1;
        const int K = part ? K2 : K1;
        if (K == 0) continue;   // uniform across block

#pragma unroll 1
        for (int k0 = 0; k0 < K; k0 += 32) {
            __syncthreads();
            // stage A tile: 128 rows x 32 bf16; 512 16B-chunks, 2/thread
#pragma unroll
            for (int i = 0; i < 2; ++i) {
                int e = i * 256 + tid;
                int r = e >> 2, kq = e & 3;
                int gr = row0 + r; if (gr > N - 1) gr = N - 1;
                uint4 v = *(const uint4*)(A + (size_t)gr * K + k0 + kq * 8);
                *(uint4*)(As + e * 8) = v;
            }
            // stage B tile from Wt (row n contiguous in k)
#pragma unroll
            for (int i = 0; i < 2; ++i) {
                int e = i * 256 + tid;
                int nn = e >> 2, kq = e & 3;
                uint4 v = *(const uint4*)(Wt + (size_t)nn * K + k0 + kq * 8);
                *(uint4*)(Bs + e * 8) = v;
            }
            __syncthreads();

            frag_ab a[4], b[4];
#pragma unroll
            for (int i = 0; i < 4; ++i)
                a[i] = *(const frag_ab*)(As + (wr * 64 + i * 16 + l15) * 32 + quad * 8);
#pragma unroll
            for (int j = 0; j < 4; ++j)
                b[j] = *(const frag_ab*)(Bs + (wc * 64 + j * 16 + l15) * 32 + quad * 8);
#pragma unroll
            for (int i = 0; i < 4; ++i)
#pragma unroll
                for (int j = 0; j < 4; ++j)
                    acc[i][j] = __builtin_amdgcn_mfma_f32_16x16x32_bf16(a[i], b[j], acc[i][j], 0, 0, 0);
        }
    }

    // epilogue: C/D layout col=lane&15, row=quad*4+reg (m89-verified)
#pragma unroll
    for (int i = 0; i < 4; ++i) {
#pragma unroll
        for (int r = 0; r < 4; ++r) {
            int row = row0 + wr * 64 + i * 16 + quad * 4 + r;
            if (row < N) {
#pragma unroll
                for (int j = 0; j < 4; ++j) {
                    int col = wc * 64 + j * 16 + l15;
                    float v = acc[i][j][r] + bias[col];
                    if (RELU) v = fmaxf(v, 0.f);
                    out[(size_t)row * 128 + col] = f2bf(v);
                }
            }
        }
    }
}

// ---------------- classifier: out[e] = dot(h2[a], h2[b]), bf16 gathers ----------------
// 16 lanes per edge, each loads 16B (8 bf16), shuffle-reduce over 16 lanes.
__global__ void classify_bf(const ushort* __restrict__ h2, const int* __restrict__ eli,
                            int EL, float* __restrict__ out) {
    int gt = blockIdx.x * blockDim.x + threadIdx.x;
    int g = gt >> 4;
    int lane = gt & 15;
    if (g >= EL) return;
    int a = eli[g], b = eli[EL + g];
    uint4 va = *((const uint4*)(h2 + (size_t)a * CH) + lane);
    uint4 vb = *((const uint4*)(h2 + (size_t)b * CH) + lane);
    float p = 0.f;
    p += bf2f((ushort)(va.x & 0xffff)) * bf2f((ushort)(vb.x & 0xffff));
    p += bf2f((ushort)(va.x >> 16))    * bf2f((ushort)(vb.x >> 16));
    p += bf2f((ushort)(va.y & 0xffff)) * bf2f((ushort)(vb.y & 0xffff));
    p += bf2f((ushort)(va.y >> 16))    * bf2f((ushort)(vb.y >> 16));
    p += bf2f((ushort)(va.z & 0xffff)) * bf2f((ushort)(vb.z & 0xffff));
    p += bf2f((ushort)(va.z >> 16))    * bf2f((ushort)(vb.z >> 16));
    p += bf2f((ushort)(va.w & 0xffff)) * bf2f((ushort)(vb.w & 0xffff));
    p += bf2f((ushort)(va.w >> 16))    * bf2f((ushort)(vb.w >> 16));
    p += __shfl_down(p, 8, 16);
    p += __shfl_down(p, 4, 16);
    p += __shfl_down(p, 2, 16);
    p += __shfl_down(p, 1, 16);
    if (lane == 0) out[g] = p;
}

extern "C" void kernel_launch(void* const* d_in, const int* in_sizes, int n_in,
                              void* d_out, int out_size, void* d_ws, size_t ws_size,
                              hipStream_t stream) {
    const float* x     = (const float*)d_in[0];
    const int*   ei    = (const int*)d_in[1];
    const int*   eli   = (const int*)d_in[2];
    const float* W_lin = (const float*)d_in[3];
    const float* b_lin = (const float*)d_in[4];
    const float* W1l   = (const float*)d_in[5];
    const float* b1    = (const float*)d_in[6];
    const float* W1r   = (const float*)d_in[7];
    const float* W2l   = (const float*)d_in[8];
    const float* b2    = (const float*)d_in[9];
    const float* W2r   = (const float*)d_in[10];
    float* out = (float*)d_out;

    const int E  = in_sizes[1] / 2;
    const int EL = in_sizes[2] / 2;
    const int N  = NODES;
    const int X  = in_sizes[0] / N;   // 384

    char* ws = (char*)d_ws;
    size_t off = 0;
    auto alloc = [&](size_t bytes) -> void* {
        void* p = ws + off;
        off += (bytes + 255) & ~(size_t)255;
        return p;
    };
    ushort* xb    = (ushort*)alloc((size_t)N * X * sizeof(ushort));
    ushort* n0    = (ushort*)alloc((size_t)N * CH * sizeof(ushort));  // h0 / h2
    ushort* n1    = (ushort*)alloc((size_t)N * CH * sizeof(ushort));  // mean1 / mean2
    ushort* n2    = (ushort*)alloc((size_t)N * CH * sizeof(ushort));  // h1
    ushort* WtLin = (ushort*)alloc((size_t)CH * X * sizeof(ushort));
    ushort* Wt1l  = (ushort*)alloc((size_t)CH * CH * sizeof(ushort));
    ushort* Wt1r  = (ushort*)alloc((size_t)CH * CH * sizeof(ushort));
    ushort* Wt2l  = (ushort*)alloc((size_t)CH * CH * sizeof(ushort));
    ushort* Wt2r  = (ushort*)alloc((size_t)CH * CH * sizeof(ushort));
    int* deg     = (int*)alloc((size_t)2 * N * sizeof(int));
    int* cursor  = deg + N;
    int* offsets = (int*)alloc((size_t)(N + 16) * sizeof(int));
    int* csr     = (int*)alloc((size_t)E * sizeof(int));
    (void)ws_size; (void)n_in; (void)out_size;

    // ---- prep: convert x and transpose-convert weights to bf16 ----
    int n4 = (N * X) / 4;
    f2bf_vec4<<<dim3((n4 + 255) / 256), dim3(256), 0, stream>>>(x, xb, n4);
    transpose_w<<<dim3((X + 1) / 2),  dim3(128, 2), 0, stream>>>(W_lin, WtLin, X);
    transpose_w<<<dim3(64), dim3(128, 2), 0, stream>>>(W1l, Wt1l, CH);
    transpose_w<<<dim3(64), dim3(128, 2), 0, stream>>>(W1r, Wt1r, CH);
    transpose_w<<<dim3(64), dim3(128, 2), 0, stream>>>(W2l, Wt2l, CH);
    transpose_w<<<dim3(64), dim3(128, 2), 0, stream>>>(W2r, Wt2r, CH);

    // ---- CSR build (rebuilt every call; ws is re-poisoned between calls) ----
    zero_ints<<<dim3((2 * N + 255) / 256), dim3(256), 0, stream>>>(deg, 2 * N);
    count_deg<<<dim3((E + 255) / 256), dim3(256), 0, stream>>>(ei, E, deg);
    scan_deg<<<dim3(1), dim3(1024), 0, stream>>>(deg, offsets, N);
    fill_csr<<<dim3((E + 255) / 256), dim3(256), 0, stream>>>(ei, E, offsets, cursor, csr);

    const int gblocks = (N + 127) / 128;

    // h0 = x @ W_lin + b_lin
    mfma_gemm<false><<<dim3(gblocks), dim3(256), 0, stream>>>(
        xb, WtLin, X, (const ushort*)nullptr, (const ushort*)nullptr, 0, b_lin, n0, N);

    // layer 1
    aggregate_bf<<<dim3((N + 3) / 4), dim3(256), 0, stream>>>(n0, csr, offsets, n1);
    mfma_gemm<true><<<dim3(gblocks), dim3(256), 0, stream>>>(
        n1, Wt1l, CH, n0, Wt1r, CH, b1, n2, N);

    // layer 2
    aggregate_bf<<<dim3((N + 3) / 4), dim3(256), 0, stream>>>(n2, csr, offsets, n1);
    mfma_gemm<false><<<dim3(gblocks), dim3(256), 0, stream>>>(
        n1, Wt2l, CH, n2, Wt2r, CH, b2, n0, N);

    // classifier
    long long cls_threads = (long long)EL * 16;
    classify_bf<<<dim3((int)((cls_threads + 255) / 256)), dim3(256), 0, stream>>>(
        n0, eli, EL, out);
}

// Round 3
// 437.592 us; speedup vs baseline: 1.6923x; 1.1556x over previous
//
#include <hip/hip_runtime.h>

#define NODES 50000
#define CH 128

using frag_ab = __attribute__((ext_vector_type(8))) short;   // 8 bf16
using frag_cd = __attribute__((ext_vector_type(4))) float;   // 4 fp32

__device__ __forceinline__ float bf2f(ushort u) {
    union { unsigned u; float f; } v; v.u = ((unsigned)u) << 16; return v.f;
}
__device__ __forceinline__ ushort f2bf(float f) {
    union { float f; unsigned u; } v; v.f = f;
    unsigned r = v.u + 0x7fff + ((v.u >> 16) & 1);   // RNE
    return (ushort)(r >> 16);
}

// ---------------- prep: fp32 -> bf16 conversions ----------------

__global__ void f2bf_vec4(const float* __restrict__ in, ushort* __restrict__ out, int n4) {
    int i = blockIdx.x * blockDim.x + threadIdx.x;
    if (i < n4) {
        float4 v = ((const float4*)in)[i];
        ushort4 o;
        o.x = f2bf(v.x); o.y = f2bf(v.y); o.z = f2bf(v.z); o.w = f2bf(v.w);
        ((ushort4*)out)[i] = o;
    }
}

// W [K,128] fp32 -> Wt [128,K] bf16 (B^T layout for MFMA b-frags)
__global__ void transpose_w(const float* __restrict__ W, ushort* __restrict__ Wt, int K) {
    int k = blockIdx.x * blockDim.y + threadIdx.y;
    int n = threadIdx.x;
    if (k < K) Wt[(size_t)n * K + k] = f2bf(W[(size_t)k * 128 + n]);
}

// ---------------- CSR build ----------------

__global__ void zero_ints(int* p, int n) {
    int i = blockIdx.x * blockDim.x + threadIdx.x;
    if (i < n) p[i] = 0;
}

__global__ void count_deg(const int* __restrict__ ei, int E, int* __restrict__ deg) {
    int e = blockIdx.x * blockDim.x + threadIdx.x;
    if (e < E) atomicAdd(&deg[ei[E + e]], 1);
}

// ---- multi-block exclusive scan over deg[N] -> offsets[0..N] ----
// phase 1: per-block (256-wide) sums
__global__ __launch_bounds__(256) void scan_p1(const int* __restrict__ deg,
                                               int* __restrict__ bsums, int N) {
    __shared__ int s[256];
    int t = threadIdx.x;
    int i = blockIdx.x * 256 + t;
    s[t] = (i < N) ? deg[i] : 0;
    __syncthreads();
    for (int off = 128; off > 0; off >>= 1) {
        if (t < off) s[t] += s[t + off];
        __syncthreads();
    }
    if (t == 0) bsums[blockIdx.x] = s[0];
}

// phase 2: single block, exclusive scan of nb (<=256) block sums in place
__global__ __launch_bounds__(256) void scan_p2(int* __restrict__ bsums, int nb) {
    __shared__ int s[256];
    int t = threadIdx.x;
    int v = (t < nb) ? bsums[t] : 0;
    s[t] = v;
    __syncthreads();
    for (int off = 1; off < 256; off <<= 1) {
        int u = (t >= off) ? s[t - off] : 0;
        __syncthreads();
        s[t] += u;
        __syncthreads();
    }
    if (t < nb) bsums[t] = s[t] - v;   // exclusive
}

// phase 3: per-block exclusive scan + block offset
__global__ __launch_bounds__(256) void scan_p3(const int* __restrict__ deg,
                                               const int* __restrict__ boffs,
                                               int* __restrict__ offsets, int N) {
    __shared__ int s[256];
    int t = threadIdx.x;
    int i = blockIdx.x * 256 + t;
    int v = (i < N) ? deg[i] : 0;
    s[t] = v;
    __syncthreads();
    for (int off = 1; off < 256; off <<= 1) {
        int u = (t >= off) ? s[t - off] : 0;
        __syncthreads();
        s[t] += u;
        __syncthreads();
    }
    int excl = boffs[blockIdx.x] + s[t] - v;
    if (i < N) offsets[i] = excl;
    if (i == N - 1) offsets[N] = excl + v;
}

__global__ void fill_csr(const int* __restrict__ ei, int E,
                         const int* __restrict__ offsets,
                         int* __restrict__ cursor, int* __restrict__ csr) {
    int e = blockIdx.x * blockDim.x + threadIdx.x;
    if (e < E) {
        int d = ei[E + e];
        int pos = atomicAdd(&cursor[d], 1);
        csr[offsets[d] + pos] = ei[e];
    }
}

// ---------------- mean aggregation over CSR, bf16 in/out ----------------
// one wave per node; lane reads ushort2 (4B) -> 64 lanes cover the 256B row.
__global__ __launch_bounds__(256) void aggregate_bf(
    const ushort* __restrict__ h, const int* __restrict__ csr,
    const int* __restrict__ offsets, ushort* __restrict__ mean) {
    int node = blockIdx.x * 4 + (threadIdx.x >> 6);
    int lane = threadIdx.x & 63;
    if (node >= NODES) return;
    int s = offsets[node], e = offsets[node + 1];
    float a0 = 0.f, a1 = 0.f;
    int n = s;
    for (; n + 1 < e; n += 2) {
        int s0 = csr[n], s1 = csr[n + 1];
        uint v0 = *(const uint*)(h + (size_t)s0 * CH + lane * 2);
        uint v1 = *(const uint*)(h + (size_t)s1 * CH + lane * 2);
        a0 += bf2f((ushort)(v0 & 0xffff)) + bf2f((ushort)(v1 & 0xffff));
        a1 += bf2f((ushort)(v0 >> 16))    + bf2f((ushort)(v1 >> 16));
    }
    if (n < e) {
        uint v0 = *(const uint*)(h + (size_t)csr[n] * CH + lane * 2);
        a0 += bf2f((ushort)(v0 & 0xffff));
        a1 += bf2f((ushort)(v0 >> 16));
    }
    float d = fmaxf((float)(e - s), 1.f);
    uint o = ((uint)f2bf(a1 / d) << 16) | (uint)f2bf(a0 / d);
    *(uint*)(mean + (size_t)node * CH + lane * 2) = o;
}

// ---------------- MFMA GEMM: out[N,128](bf16) = A1@W1 + A2@W2 + bias ----------------
template <bool RELU>
__global__ __launch_bounds__(256) void mfma_gemm(
    const ushort* __restrict__ A1, const ushort* __restrict__ Wt1, int K1,
    const ushort* __restrict__ A2, const ushort* __restrict__ Wt2, int K2,
    const float* __restrict__ bias, ushort* __restrict__ out, int N)
{
    __shared__ ushort As[128 * 32];
    __shared__ ushort Bs[128 * 32];
    const int tid = threadIdx.x;
    const int lane = tid & 63;
    const int wave = tid >> 6;
    const int wr = wave >> 1;
    const int wc = wave & 1;
    const int row0 = blockIdx.x * 128;
    const int l15 = lane & 15;
    const int quad = lane >> 4;

    frag_cd acc[4][4];
#pragma unroll
    for (int i = 0; i < 4; ++i)
#pragma unroll
        for (int j = 0; j < 4; ++j) acc[i][j] = (frag_cd){0.f, 0.f, 0.f, 0.f};

#pragma unroll 1
    for (int part = 0; part < 2; ++part) {
        const ushort* A  = part ? A2 : A1;
        const ushort* Wt = part ? Wt2 : Wt1;
        const int K = part ? K2 : K1;
        if (K == 0) continue;   // uniform across block

#pragma unroll 1
        for (int k0 = 0; k0 < K; k0 += 32) {
            __syncthreads();
#pragma unroll
            for (int i = 0; i < 2; ++i) {
                int e = i * 256 + tid;
                int r = e >> 2, kq = e & 3;
                int gr = row0 + r; if (gr > N - 1) gr = N - 1;
                uint4 v = *(const uint4*)(A + (size_t)gr * K + k0 + kq * 8);
                *(uint4*)(As + e * 8) = v;
            }
#pragma unroll
            for (int i = 0; i < 2; ++i) {
                int e = i * 256 + tid;
                int nn = e >> 2, kq = e & 3;
                uint4 v = *(const uint4*)(Wt + (size_t)nn * K + k0 + kq * 8);
                *(uint4*)(Bs + e * 8) = v;
            }
            __syncthreads();

            frag_ab a[4], b[4];
#pragma unroll
            for (int i = 0; i < 4; ++i)
                a[i] = *(const frag_ab*)(As + (wr * 64 + i * 16 + l15) * 32 + quad * 8);
#pragma unroll
            for (int j = 0; j < 4; ++j)
                b[j] = *(const frag_ab*)(Bs + (wc * 64 + j * 16 + l15) * 32 + quad * 8);
#pragma unroll
            for (int i = 0; i < 4; ++i)
#pragma unroll
                for (int j = 0; j < 4; ++j)
                    acc[i][j] = __builtin_amdgcn_mfma_f32_16x16x32_bf16(a[i], b[j], acc[i][j], 0, 0, 0);
        }
    }

    // epilogue: C/D layout col=lane&15, row=quad*4+reg (m89-verified)
#pragma unroll
    for (int i = 0; i < 4; ++i) {
#pragma unroll
        for (int r = 0; r < 4; ++r) {
            int row = row0 + wr * 64 + i * 16 + quad * 4 + r;
            if (row < N) {
#pragma unroll
                for (int j = 0; j < 4; ++j) {
                    int col = wc * 64 + j * 16 + l15;
                    float v = acc[i][j][r] + bias[col];
                    if (RELU) v = fmaxf(v, 0.f);
                    out[(size_t)row * 128 + col] = f2bf(v);
                }
            }
        }
    }
}

// ---------------- classifier: out[e] = dot(h2[a], h2[b]), bf16 gathers ----------------
__global__ void classify_bf(const ushort* __restrict__ h2, const int* __restrict__ eli,
                            int EL, float* __restrict__ out) {
    int gt = blockIdx.x * blockDim.x + threadIdx.x;
    int g = gt >> 4;
    int lane = gt & 15;
    if (g >= EL) return;
    int a = eli[g], b = eli[EL + g];
    uint4 va = *((const uint4*)(h2 + (size_t)a * CH) + lane);
    uint4 vb = *((const uint4*)(h2 + (size_t)b * CH) + lane);
    float p = 0.f;
    p += bf2f((ushort)(va.x & 0xffff)) * bf2f((ushort)(vb.x & 0xffff));
    p += bf2f((ushort)(va.x >> 16))    * bf2f((ushort)(vb.x >> 16));
    p += bf2f((ushort)(va.y & 0xffff)) * bf2f((ushort)(vb.y & 0xffff));
    p += bf2f((ushort)(va.y >> 16))    * bf2f((ushort)(vb.y >> 16));
    p += bf2f((ushort)(va.z & 0xffff)) * bf2f((ushort)(vb.z & 0xffff));
    p += bf2f((ushort)(va.z >> 16))    * bf2f((ushort)(vb.z >> 16));
    p += bf2f((ushort)(va.w & 0xffff)) * bf2f((ushort)(vb.w & 0xffff));
    p += bf2f((ushort)(va.w >> 16))    * bf2f((ushort)(vb.w >> 16));
    p += __shfl_down(p, 8, 16);
    p += __shfl_down(p, 4, 16);
    p += __shfl_down(p, 2, 16);
    p += __shfl_down(p, 1, 16);
    if (lane == 0) out[g] = p;
}

extern "C" void kernel_launch(void* const* d_in, const int* in_sizes, int n_in,
                              void* d_out, int out_size, void* d_ws, size_t ws_size,
                              hipStream_t stream) {
    const float* x     = (const float*)d_in[0];
    const int*   ei    = (const int*)d_in[1];
    const int*   eli   = (const int*)d_in[2];
    const float* W_lin = (const float*)d_in[3];
    const float* b_lin = (const float*)d_in[4];
    const float* W1l   = (const float*)d_in[5];
    const float* b1    = (const float*)d_in[6];
    const float* W1r   = (const float*)d_in[7];
    const float* W2l   = (const float*)d_in[8];
    const float* b2    = (const float*)d_in[9];
    const float* W2r   = (const float*)d_in[10];
    float* out = (float*)d_out;

    const int E  = in_sizes[1] / 2;
    const int EL = in_sizes[2] / 2;
    const int N  = NODES;
    const int X  = in_sizes[0] / N;   // 384

    char* ws = (char*)d_ws;
    size_t off = 0;
    auto alloc = [&](size_t bytes) -> void* {
        void* p = ws + off;
        off += (bytes + 255) & ~(size_t)255;
        return p;
    };
    ushort* xb    = (ushort*)alloc((size_t)N * X * sizeof(ushort));
    ushort* n0    = (ushort*)alloc((size_t)N * CH * sizeof(ushort));  // h0 / h2
    ushort* n1    = (ushort*)alloc((size_t)N * CH * sizeof(ushort));  // mean1 / mean2
    ushort* n2    = (ushort*)alloc((size_t)N * CH * sizeof(ushort));  // h1
    ushort* WtLin = (ushort*)alloc((size_t)CH * X * sizeof(ushort));
    ushort* Wt1l  = (ushort*)alloc((size_t)CH * CH * sizeof(ushort));
    ushort* Wt1r  = (ushort*)alloc((size_t)CH * CH * sizeof(ushort));
    ushort* Wt2l  = (ushort*)alloc((size_t)CH * CH * sizeof(ushort));
    ushort* Wt2r  = (ushort*)alloc((size_t)CH * CH * sizeof(ushort));
    int* deg     = (int*)alloc((size_t)2 * N * sizeof(int));
    int* cursor  = deg + N;
    int* offsets = (int*)alloc((size_t)(N + 16) * sizeof(int));
    int* csr     = (int*)alloc((size_t)E * sizeof(int));
    int* bsums   = (int*)alloc((size_t)256 * sizeof(int));
    (void)ws_size; (void)n_in; (void)out_size;

    // ---- prep: convert x and transpose-convert weights to bf16 ----
    int n4 = (N * X) / 4;
    f2bf_vec4<<<dim3((n4 + 255) / 256), dim3(256), 0, stream>>>(x, xb, n4);
    transpose_w<<<dim3((X + 1) / 2),  dim3(128, 2), 0, stream>>>(W_lin, WtLin, X);
    transpose_w<<<dim3(64), dim3(128, 2), 0, stream>>>(W1l, Wt1l, CH);
    transpose_w<<<dim3(64), dim3(128, 2), 0, stream>>>(W1r, Wt1r, CH);
    transpose_w<<<dim3(64), dim3(128, 2), 0, stream>>>(W2l, Wt2l, CH);
    transpose_w<<<dim3(64), dim3(128, 2), 0, stream>>>(W2r, Wt2r, CH);

    // ---- CSR build (rebuilt every call; ws is re-poisoned between calls) ----
    const int nb = (N + 255) / 256;   // 196 blocks <= 256
    zero_ints<<<dim3((2 * N + 255) / 256), dim3(256), 0, stream>>>(deg, 2 * N);
    count_deg<<<dim3((E + 255) / 256), dim3(256), 0, stream>>>(ei, E, deg);
    scan_p1<<<dim3(nb), dim3(256), 0, stream>>>(deg, bsums, N);
    scan_p2<<<dim3(1), dim3(256), 0, stream>>>(bsums, nb);
    scan_p3<<<dim3(nb), dim3(256), 0, stream>>>(deg, bsums, offsets, N);
    fill_csr<<<dim3((E + 255) / 256), dim3(256), 0, stream>>>(ei, E, offsets, cursor, csr);

    const int gblocks = (N + 127) / 128;

    // h0 = x @ W_lin + b_lin
    mfma_gemm<false><<<dim3(gblocks), dim3(256), 0, stream>>>(
        xb, WtLin, X, (const ushort*)nullptr, (const ushort*)nullptr, 0, b_lin, n0, N);

    // layer 1
    aggregate_bf<<<dim3((N + 3) / 4), dim3(256), 0, stream>>>(n0, csr, offsets, n1);
    mfma_gemm<true><<<dim3(gblocks), dim3(256), 0, stream>>>(
        n1, Wt1l, CH, n0, Wt1r, CH, b1, n2, N);

    // layer 2
    aggregate_bf<<<dim3((N + 3) / 4), dim3(256), 0, stream>>>(n2, csr, offsets, n1);
    mfma_gemm<false><<<dim3(gblocks), dim3(256), 0, stream>>>(
        n1, Wt2l, CH, n2, Wt2r, CH, b2, n0, N);

    // classifier
    long long cls_threads = (long long)EL * 16;
    classify_bf<<<dim3((int)((cls_threads + 255) / 256)), dim3(256), 0, stream>>>(
        n0, eli, EL, out);
}